// Round 4
// baseline (1335.666 us; speedup 1.0000x reference)
//
#include <hip/hip_runtime.h>

typedef __bf16 bf16_t;
typedef __bf16 bf16x4 __attribute__((ext_vector_type(4)));
typedef __bf16 bf16x8 __attribute__((ext_vector_type(8)));
typedef float  f32x4  __attribute__((ext_vector_type(4)));
typedef int    i32x4  __attribute__((ext_vector_type(4)));

#define HID    128
#define DIO    80
#define G4     512
#define TSTEP  512
#define BB     8      // batch rows per block (half-filled MFMA N-dim)
#define NBATCH 4096
#define NBLK   (NBATCH / BB)   // 512 blocks -> 2 blocks/CU
#define HSTR   136    // LDS row stride (bf16 elems)

// Fragment layout (identical indexing for A- and B-operand of 16x16x32 bf16):
// frag tile (ntile,kt): elem[lane*8+j] = W[n=ntile*16+(lane&15)][k=kt*32+(lane>>4)*8+j]
__device__ __align__(16) bf16_t g_weff_frags[128 * 512];
__device__ __align__(16) bf16_t g_whh_frags[128 * 512];
__device__ __align__(16) bf16_t g_wfc_frags[20 * 512];
__device__ float g_weff[G4 * HID];
__device__ float g_beff[G4];
__device__ float g_b1[G4];

// W_eff = W_hh + W_ih @ W_fc ; b_eff = b_ih + b_hh + W_ih @ b_fc ; b1 = b_ih + b_hh
__global__ void k_weff(const float* __restrict__ W_ih, const float* __restrict__ W_hh,
                       const float* __restrict__ b_ih, const float* __restrict__ b_hh,
                       const float* __restrict__ W_fc, const float* __restrict__ b_fc) {
  int gid = blockIdx.x * blockDim.x + threadIdx.x;
  int g = gid >> 7, k = gid & 127;
  float acc = W_hh[g * HID + k];
#pragma unroll 8
  for (int d = 0; d < DIO; ++d)
    acc = fmaf(W_ih[g * DIO + d], W_fc[d * HID + k], acc);
  g_weff[g * HID + k] = acc;
  if (k == 0) {
    float bb = b_ih[g] + b_hh[g];
    g_b1[g] = bb;
    float be = bb;
    for (int d = 0; d < DIO; ++d) be = fmaf(W_ih[g * DIO + d], b_fc[d], be);
    g_beff[g] = be;
  }
}

__global__ void k_frag(const float* __restrict__ W_hh, const float* __restrict__ W_fc) {
  int tile = blockIdx.x;  // 0..275
  int lane = threadIdx.x;
  int c = lane & 15, q = lane >> 4;
  if (tile < 128) {
    int gtile = tile >> 2, kt = tile & 3;
    int n = gtile * 16 + c;
#pragma unroll
    for (int j = 0; j < 8; ++j)
      g_weff_frags[tile * 512 + lane * 8 + j] = (bf16_t)g_weff[n * HID + kt * 32 + q * 8 + j];
  } else if (tile < 256) {
    int t2 = tile - 128;
    int gtile = t2 >> 2, kt = t2 & 3;
    int n = gtile * 16 + c;
#pragma unroll
    for (int j = 0; j < 8; ++j)
      g_whh_frags[t2 * 512 + lane * 8 + j] = (bf16_t)W_hh[n * HID + kt * 32 + q * 8 + j];
  } else {
    int t2 = tile - 256;  // 0..19
    int yt = t2 >> 2, kt = t2 & 3;
    int n = yt * 16 + c;
#pragma unroll
    for (int j = 0; j < 8; ++j)
      g_wfc_frags[t2 * 512 + lane * 8 + j] = (bf16_t)W_fc[n * HID + kt * 32 + q * 8 + j];
  }
}

#define LOG2E 1.4426950408889634f

// 512 blocks x 512 threads; 8 batch rows/block -> 2 independent blocks (barrier
// groups) per CU, 4 waves/SIMD. Register budget <=128: only Wg/hf/acc/cst live
// in regs; W_fc frags + biases staged in LDS, broadcast-read each step.
__global__ __launch_bounds__(512, 4) void k_lstm(const float* __restrict__ h0,
                                                 const float* __restrict__ b_fc,
                                                 float* __restrict__ out) {
  __shared__ __align__(16) bf16_t hbuf[2][16 * HSTR];
  __shared__ __align__(16) bf16_t wyl[20 * 512];   // W_fc fragment copy
  __shared__ __align__(16) float beffl[G4];
  __shared__ __align__(16) float b1l[G4];
  __shared__ __align__(16) float bfcl[DIO];
  const int tid = threadIdx.x;
  const int lane = tid & 63;
  const int w = tid >> 6;  // 0..7
  const int c = lane & 15, q = lane >> 4;
  const int b0 = blockIdx.x * BB;

  // --- one-time staging ---
  // zero rows 8..15 of both h buffers (never written again -> clean MFMA cols)
  for (int i = tid; i < 2 * 8 * HID; i += 512) {
    int buf = i >> 10, idx = i & 1023;
    hbuf[buf][(8 + (idx >> 7)) * HSTR + (idx & 127)] = (bf16_t)0.0f;
  }
  // h0 rows 0..7 -> buf0
  for (int i = tid; i < BB * HID; i += 512) {
    int r = i >> 7, k = i & 127;
    hbuf[0][r * HSTR + k] = (bf16_t)h0[(long)(b0 + r) * HID + k];
  }
  // W_fc frags -> LDS (as dwords)
  for (int i = tid; i < 20 * 512 / 2; i += 512)
    ((int*)wyl)[i] = ((const int*)g_wfc_frags)[i];
  // biases -> LDS
  beffl[tid < G4 ? tid : 0] = g_beff[tid < G4 ? tid : 0];
  b1l[tid < G4 ? tid : 0] = g_b1[tid < G4 ? tid : 0];
  if (tid < DIO) bfcl[tid] = b_fc[tid];

  i32x4 Wg[4][4];  // [gate][ktile] — 64 VGPRs, the only big resident array
  auto load_wg = [&](const bf16_t* frags) {
#pragma unroll
    for (int G = 0; G < 4; ++G)
#pragma unroll
      for (int kt = 0; kt < 4; ++kt)
        Wg[G][kt] = *(const i32x4*)&frags[((G * 8 + w) * 4 + kt) * 512 + lane * 8];
  };

  f32x4 cst = (f32x4){0, 0, 0, 0};
  bf16x8 hf[4];

  __syncthreads();
#pragma unroll
  for (int kt = 0; kt < 4; ++kt)
    hf[kt] = *(const bf16x8*)&hbuf[0][c * HSTR + kt * 32 + q * 8];

  float* outp = out + (long)(b0 + c) * TSTEP * DIO + w * 16 + q * 4;

  // fused-rcp LSTM elementwise: 5 exp2 + 3 rcp per unit (was 10 trans)
  auto elemwise = [&](f32x4 acc[4], int buf) {
    bf16x4 hv;
#pragma unroll
    for (int r = 0; r < 4; ++r) {
      float a = __builtin_amdgcn_exp2f(acc[0][r] * -LOG2E);        // e^-i
      float b = __builtin_amdgcn_exp2f(acc[2][r] * (2.f * LOG2E)); // e^2g
      float e = __builtin_amdgcn_exp2f(acc[1][r] * -LOG2E);        // e^-f
      float u = __builtin_amdgcn_exp2f(acc[3][r] * -LOG2E);        // e^-o
      float sf = __builtin_amdgcn_rcpf(1.0f + e);
      float itg = (b - 1.0f) * __builtin_amdgcn_rcpf(fmaf(a, b, a + b) + 1.0f);
      float cn = fmaf(sf, cst[r], itg);
      cst[r] = cn;
      float v = __builtin_amdgcn_exp2f(cn * (2.f * LOG2E));        // e^2c
      hv[r] = (bf16_t)((v - 1.0f) * __builtin_amdgcn_rcpf(fmaf(u, v, u + v) + 1.0f));
    }
    if (c < 8) *(bf16x4*)&hbuf[buf][c * HSTR + w * 16 + q * 4] = hv;
  };

  // ---- step 1: gates = h0 @ W_hh^T + (b_ih+b_hh) ----
  load_wg(g_whh_frags);
  {
    f32x4 acc[4];
#pragma unroll
    for (int G = 0; G < 4; ++G)
      acc[G] = *(const f32x4*)&b1l[(G * 8 + w) * 16 + q * 4];
#pragma unroll
    for (int kt = 0; kt < 4; ++kt)
#pragma unroll
      for (int G = 0; G < 4; ++G)
        acc[G] = __builtin_amdgcn_mfma_f32_16x16x32_bf16(
            __builtin_bit_cast(bf16x8, Wg[G][kt]), hf[kt], acc[G], 0, 0, 0);
    elemwise(acc, 1);
    __syncthreads();
#pragma unroll
    for (int kt = 0; kt < 4; ++kt)
      hf[kt] = *(const bf16x8*)&hbuf[1][c * HSTR + kt * 32 + q * 8];
  }

  // ---- steps 2..512: fused recurrence ----
  load_wg(g_weff_frags);
#pragma unroll 1
  for (int t = 2; t <= TSTEP; ++t) {
    f32x4 acc[4];
#pragma unroll
    for (int G = 0; G < 4; ++G)
      acc[G] = *(const f32x4*)&beffl[(G * 8 + w) * 16 + q * 4];
#pragma unroll
    for (int kt = 0; kt < 4; ++kt)
#pragma unroll
      for (int G = 0; G < 4; ++G)
        acc[G] = __builtin_amdgcn_mfma_f32_16x16x32_bf16(
            __builtin_bit_cast(bf16x8, Wg[G][kt]), hf[kt], acc[G], 0, 0, 0);

    // y(t-1) from hf (= h(t-1)) — issued after gate MFMAs, off critical path
    if (w < 5) {
      f32x4 ya = *(const f32x4*)&bfcl[w * 16 + q * 4];
#pragma unroll
      for (int kt = 0; kt < 4; ++kt)
        ya = __builtin_amdgcn_mfma_f32_16x16x32_bf16(
            *(const bf16x8*)&wyl[(w * 4 + kt) * 512 + lane * 8], hf[kt], ya, 0, 0, 0);
      if (c < 8) *(f32x4*)&outp[(long)(t - 2) * DIO] = ya;
    }

    const int buf = t & 1;
    elemwise(acc, buf);
    __syncthreads();
#pragma unroll
    for (int kt = 0; kt < 4; ++kt)
      hf[kt] = *(const bf16x8*)&hbuf[buf][c * HSTR + kt * 32 + q * 8];
  }

  // epilogue: y(512)
  if (w < 5) {
    f32x4 ya = *(const f32x4*)&bfcl[w * 16 + q * 4];
#pragma unroll
    for (int kt = 0; kt < 4; ++kt)
      ya = __builtin_amdgcn_mfma_f32_16x16x32_bf16(
          *(const bf16x8*)&wyl[(w * 4 + kt) * 512 + lane * 8], hf[kt], ya, 0, 0, 0);
    if (c < 8) *(f32x4*)&outp[(long)(TSTEP - 1) * DIO] = ya;
  }
}

extern "C" void kernel_launch(void* const* d_in, const int* in_sizes, int n_in,
                              void* d_out, int out_size, void* d_ws, size_t ws_size,
                              hipStream_t stream) {
  const float* h0   = (const float*)d_in[0];
  const float* W_ih = (const float*)d_in[1];
  const float* W_hh = (const float*)d_in[2];
  const float* b_ih = (const float*)d_in[3];
  const float* b_hh = (const float*)d_in[4];
  const float* W_fc = (const float*)d_in[5];
  const float* b_fc = (const float*)d_in[6];
  float* out = (float*)d_out;

  k_weff<<<256, 256, 0, stream>>>(W_ih, W_hh, b_ih, b_hh, W_fc, b_fc);
  k_frag<<<276, 64, 0, stream>>>(W_hh, W_fc);
  k_lstm<<<NBLK, 512, 0, stream>>>(h0, b_fc, out);
}